// Round 7
// baseline (304.150 us; speedup 1.0000x reference)
//
#include <hip/hip_runtime.h>
#include <hip/hip_bf16.h>

#define SEQ 2048
#define LDQKV 6144

typedef __attribute__((ext_vector_type(8))) __bf16 bf16x8;
typedef __attribute__((ext_vector_type(4))) __bf16 bf16x4;
typedef __attribute__((ext_vector_type(4))) float f32x4;

__device__ __forceinline__ void gload_lds16(const void* g, void* l) {
  __builtin_amdgcn_global_load_lds((__attribute__((address_space(1))) void*)(g),
                                   (__attribute__((address_space(3))) void*)(l), 16, 0, 0);
}

#define VMW(n) asm volatile("s_waitcnt vmcnt(" #n ")" ::: "memory")

// ---------------- all f32 -> bf16 conversions in one kernel ----------------
struct CvtArgs {
  const float* src0; const float* src1; const float* src2; const float* src3; const float* src4;
  __bf16* dst0; __bf16* dst1; __bf16* dst2; __bf16* dst3; __bf16* dst4;
};
__global__ __launch_bounds__(256) void cvt_all(CvtArgs a) {
  int b = blockIdx.x;
  const float* s; __bf16* d; int boff;
  if (b < 8192)       { s = a.src0; d = a.dst0; boff = b; }
  else if (b < 24576) { s = a.src1; d = a.dst1; boff = b - 8192; }
  else if (b < 28672) { s = a.src2; d = a.dst2; boff = b - 24576; }
  else if (b < 32768) { s = a.src3; d = a.dst3; boff = b - 28672; }
  else                { s = a.src4; d = a.dst4; boff = b - 32768; }
  long i = ((long)boff * 256 + threadIdx.x) * 4;
  f32x4 v = *(const f32x4*)(s + i);
  bf16x4 o;
  #pragma unroll
  for (int j = 0; j < 4; ++j) o[j] = (__bf16)v[j];
  *(bf16x4*)(d + i) = o;
}

// ---------------- RoPE cos/sin table (reference fp16 inv_freq chain) ----------------
__global__ __launch_bounds__(256) void rope_tab_k(const int* __restrict__ pos,
                                                  float* __restrict__ tab) {
  int i = blockIdx.x * 256 + threadIdx.x;
  int s = i >> 6, j = i & 63;
  float p = (float)pos[s];
  float pw = powf(10000.0f, (float)j * (1.0f / 64.0f));
  _Float16 ph = (_Float16)pw;
  _Float16 ivh = (_Float16)(1.0f / (float)ph);
  float freq = (float)ivh;
  float th = p * freq;
  tab[i] = cosf(th);
  tab[SEQ * 64 + i] = sinf(th);
}

// ---------------- RoPE applied in-place to Q (32 heads) and K (8 heads) ----------------
__global__ __launch_bounds__(256) void rope_apply_k(__bf16* __restrict__ qkv,
                                                    const float* __restrict__ tab) {
  int i = blockIdx.x * 256 + threadIdx.x;
  int dc = i & 7;
  int ht = (i >> 3) % 40;
  int s = i / 320;
  long col = (ht < 32) ? (long)ht * 128 : (long)4096 + (long)(ht - 32) * 128;
  __bf16* p = qkv + (long)s * LDQKV + col + dc * 8;
  bf16x8 lo = *(bf16x8*)p;
  bf16x8 hi = *(bf16x8*)(p + 64);
  const float* tc = tab + (long)s * 64 + dc * 8;
  const float* ts = tc + SEQ * 64;
  bf16x8 lo2, hi2;
  #pragma unroll
  for (int e = 0; e < 8; ++e) {
    float c = tc[e], sn = ts[e];
    float lv = (float)lo[e], hv = (float)hi[e];
    lo2[e] = (__bf16)(lv * c - hv * sn);
    hi2[e] = (__bf16)(hv * c + lv * sn);
  }
  *(bf16x8*)p = lo2;
  *(bf16x8*)(p + 64) = hi2;
}

// ---------------- m201-cadence NT GEMM: C[M][N] = A[M][K]*B[N][K]^T ----------------
// BM=128, BN=384|256 -> grid 16x16=256 blocks = 1/CU. 512 thr / 8 waves (2M x 4N),
// per-wave 64 x (BN/4). BK=64 split in kf-halves; phase = (kf, mi-half), 12|8 MFMA.
// LDS: A [2][128][64] (32KB) + B [2][2][BN][32] (96|64KB), double-buffered.
// Stage: full next tile issued 2 gloads/phase; vmcnt(4) after ph1, vmcnt(BCH) after
// ph3 (never 0 mid-loop). Double-barrier phase body, lgkmcnt(0) before MFMA.
template<int BN, bool OUT_BF16>
__global__ __launch_bounds__(512, 2) void gemm8p(const __bf16* __restrict__ A,
                                                 const __bf16* __restrict__ B,
                                                 void* __restrict__ C,
                                                 int K, int ldc) {
  constexpr int NI  = BN / 64;     // per-wave n-frags (6 | 4)
  constexpr int BCH = BN / 128;    // B chunks per kf-half (3 | 2)
  constexpr int BOFF = 16384;      // elems: A region = 2 x 8192
  constexpr int BBUF = 2 * BN * 32;
  extern __shared__ __bf16 lds[];

  const int tid = threadIdx.x;
  const int wave = tid >> 6, lane = tid & 63;
  const int l15 = lane & 15, l4 = lane >> 4;
  const int wm = wave >> 2, wn = wave & 3;

  const int orig = blockIdx.x;                 // XCD-bijective swizzle (256 % 8 == 0)
  const int swz = (orig & 7) * 32 + (orig >> 3);
  const int bx = swz & 15, by = swz >> 4;
  const long brow = (long)bx * 128, bcol = (long)by * BN;

  const int aRow = tid >> 3, aCol = ((tid & 7) ^ ((tid >> 3) & 7)) * 8;
  const int bRow = tid >> 2, bCol = ((tid & 3) ^ ((tid >> 3) & 3)) * 8;
  const int NT = K >> 6;

  // load index order: 0,1 = A chunks; 2..1+BCH = B kf0; 2+BCH.. = B kf1
  auto issue = [&](int nb, int idx, int t) {
    if (idx < 2) {
      gload_lds16(A + (brow + idx * 64 + aRow) * (long)K + t * 64 + aCol,
                  lds + nb * 8192 + idx * 4096 + wave * 512);
    } else {
      const int kf = (idx - 2) / BCH, cb = (idx - 2) % BCH;
      gload_lds16(B + (bcol + cb * 128 + bRow) * (long)K + t * 64 + kf * 32 + bCol,
                  lds + BOFF + nb * BBUF + kf * (BN * 32) + cb * 4096 + wave * 512);
    }
  };

  bf16x8 af[2], bfr[NI];
  auto readA2 = [&](int buf, int kf, int mih) {
    #pragma unroll
    for (int m2 = 0; m2 < 2; ++m2) {
      int r = wm * 64 + (mih * 2 + m2) * 16 + l15;
      af[m2] = *(const bf16x8*)&lds[buf * 8192 + r * 64 + ((kf * 4 + l4) ^ (r & 7)) * 8];
    }
  };
  auto readBN = [&](int buf, int kf) {
    #pragma unroll
    for (int ni = 0; ni < NI; ++ni) {
      int r = wn * (NI * 16) + ni * 16 + l15;
      int g = l4 ^ ((r >> 1) & 3);
      bfr[ni] = *(const bf16x8*)&lds[BOFF + buf * BBUF + kf * (BN * 32) + r * 32 + g * 8];
    }
  };

  f32x4 acc[4][NI] = {};
  auto mfma2 = [&](int mih) {
    __builtin_amdgcn_s_setprio(1);
    #pragma unroll
    for (int m2 = 0; m2 < 2; ++m2)
      #pragma unroll
      for (int ni = 0; ni < NI; ++ni)
        acc[mih * 2 + m2][ni] =
            __builtin_amdgcn_mfma_f32_16x16x32_bf16(af[m2], bfr[ni], acc[mih * 2 + m2][ni], 0, 0, 0);
    __builtin_amdgcn_s_setprio(0);
  };

  #define PH_PRE()  do { __builtin_amdgcn_sched_barrier(0); __builtin_amdgcn_s_barrier(); \
                         asm volatile("s_waitcnt lgkmcnt(0)" ::: "memory"); \
                         __builtin_amdgcn_sched_barrier(0); } while (0)

  // prologue: stage tile 0 fully; land A + B-kf0, keep B-kf1 in flight
  #pragma unroll
  for (int i = 0; i < 2 + 2 * BCH; ++i) issue(0, i, 0);
  if constexpr (BCH == 3) VMW(3); else VMW(2);
  __builtin_amdgcn_s_barrier();

  for (int t = 0; t < NT; ++t) {
    const int buf = t & 1, nb = buf ^ 1;
    const bool pf = (t + 1 < NT);
    const int t1 = t + 1;
    // ph0: kf0, rows 0-31
    readBN(buf, 0); readA2(buf, 0, 0);
    if (pf) { issue(nb, 0, t1); issue(nb, 1, t1); }
    PH_PRE();
    mfma2(0);
    __builtin_amdgcn_s_barrier();
    // ph1: kf0, rows 32-63
    readA2(buf, 0, 1);
    if (pf) { issue(nb, 2, t1); issue(nb, 3, t1); }
    PH_PRE();
    mfma2(1);
    if (pf) VMW(4); else VMW(0);      // drain own B-kf1(t) (and older)
    __builtin_amdgcn_s_barrier();
    // ph2: kf1, rows 0-31
    readBN(buf, 1); readA2(buf, 1, 0);
    if (pf) { issue(nb, 4, t1); issue(nb, 5, t1); }
    PH_PRE();
    mfma2(0);
    __builtin_amdgcn_s_barrier();
    // ph3: kf1, rows 32-63
    readA2(buf, 1, 1);
    if (pf) { if constexpr (BCH == 3) { issue(nb, 6, t1); issue(nb, 7, t1); } }
    PH_PRE();
    mfma2(1);
    if (pf) { if constexpr (BCH == 3) VMW(3); else VMW(2); }  // land A+B-kf0(t+1)
    __builtin_amdgcn_s_barrier();
  }
  #undef PH_PRE

  #pragma unroll
  for (int mi = 0; mi < 4; ++mi)
    #pragma unroll
    for (int ni = 0; ni < NI; ++ni)
      #pragma unroll
      for (int j = 0; j < 4; ++j) {
        long rr = brow + wm * 64 + mi * 16 + l4 * 4 + j;
        long cc = bcol + wn * (NI * 16) + ni * 16 + l15;
        float v = acc[mi][ni][j];
        if (OUT_BF16) ((__bf16*)C)[rr * ldc + cc] = (__bf16)v;
        else          ((float*)C)[rr * ldc + cc] = v;
      }
}

// ---------------- flash attention v3b (causal, GQA 4:1) ---------------- (unchanged)
__global__ __launch_bounds__(256) void flash_k(const __bf16* __restrict__ qkv,
                                               __bf16* __restrict__ ctx) {
  __shared__ __align__(16) __bf16 Kl[8192];      // [64][128] xor-swizzled
  __shared__ __align__(16) __bf16 Vt[8192];      // [128][64] col-swizzled
  __shared__ __align__(16) __bf16 Pl[4][1024];   // per-wave [16][64] swizzled

  const int bid = blockIdx.x;
  const int h = bid & 31;
  const int qt = 31 - (bid >> 5);
  const int kvh = h >> 2;
  const int q0 = qt * 64;
  const int tid = threadIdx.x, wave = tid >> 6, lane = tid & 63;
  const int l15 = lane & 15, l4 = lane >> 4;
  const int d2 = tid & 63, grp = tid >> 6;

  const __bf16* Qp = qkv + (long)h * 128;
  const __bf16* Kp = qkv + 4096 + (long)kvh * 128;
  const __bf16* Vp = qkv + 5120 + (long)kvh * 128;

  bf16x8 aq[4];
  {
    long qr = q0 + wave * 16 + l15;
    #pragma unroll
    for (int ks = 0; ks < 4; ++ks)
      aq[ks] = *(const bf16x8*)(Qp + qr * LDQKV + ks * 32 + l4 * 8);
  }
  f32x4 accO[8] = {};
  float lsum[4] = {0.f, 0.f, 0.f, 0.f};
  const float cexp = 0.08838834764831845f * 1.4426950408889634f;

  for (int kv0 = 0; kv0 <= q0; kv0 += 64) {
    __syncthreads();
    #pragma unroll
    for (int i = 0; i < 4; ++i) {
      int fo = i * 2048 + wave * 512 + lane * 8;
      int r = fo >> 7, c = fo & 127;
      int cs = c ^ ((r & 7) << 3);
      gload_lds16(Kp + (long)(kv0 + r) * LDQKV + cs, &Kl[i * 2048 + wave * 512]);
    }
    unsigned int vv[2][8];
    #pragma unroll
    for (int rep = 0; rep < 2; ++rep) {
      int cch = grp * 2 + rep;
      #pragma unroll
      for (int i = 0; i < 8; ++i)
        vv[rep][i] = *(const unsigned int*)(Vp + (long)(kv0 + cch * 8 + i) * LDQKV + 2 * d2);
    }
    #pragma unroll
    for (int rep = 0; rep < 2; ++rep) {
      int cch = grp * 2 + rep;
      #pragma unroll
      for (int half = 0; half < 2; ++half) {
        bf16x8 w;
        #pragma unroll
        for (int i = 0; i < 8; ++i)
          w[i] = __builtin_bit_cast(__bf16, (unsigned short)(vv[rep][i] >> (16 * half)));
        int d = 2 * d2 + half;
        *(bf16x8*)&Vt[d * 64 + ((cch * 8) ^ ((d2 & 7) * 8))] = w;
      }
    }
    __syncthreads();

    f32x4 s[4];
    #pragma unroll
    for (int t = 0; t < 4; ++t) s[t] = f32x4{0.f, 0.f, 0.f, 0.f};
    __builtin_amdgcn_s_setprio(1);
    #pragma unroll
    for (int t = 0; t < 4; ++t) {
      int r = t * 16 + l15;
      #pragma unroll
      for (int ks = 0; ks < 4; ++ks) {
        bf16x8 bk = *(const bf16x8*)&Kl[r * 128 + ((ks * 32 + l4 * 8) ^ ((r & 7) << 3))];
        s[t] = __builtin_amdgcn_mfma_f32_16x16x32_bf16(aq[ks], bk, s[t], 0, 0, 0);
      }
    }
    __builtin_amdgcn_s_setprio(0);

    const bool lastStep = (kv0 == q0);
    float pout[4][4];
    #pragma unroll
    for (int t = 0; t < 4; ++t)
      #pragma unroll
      for (int j = 0; j < 4; ++j) {
        float p = exp2f(s[t][j] * cexp);
        if (lastStep) {
          int qg = wave * 16 + l4 * 4 + j;
          int kg = t * 16 + l15;
          if (kg > qg) p = 0.f;
        }
        pout[t][j] = p;
      }
    #pragma unroll
    for (int j = 0; j < 4; ++j)
      lsum[j] += (pout[0][j] + pout[1][j]) + (pout[2][j] + pout[3][j]);

    #pragma unroll
    for (int t = 0; t < 4; ++t)
      #pragma unroll
      for (int j = 0; j < 4; ++j) {
        int r = l4 * 4 + j;
        int c = t * 16 + l15;
        Pl[wave][r * 64 + (c ^ ((r & 7) << 3))] = (__bf16)pout[t][j];
      }
    asm volatile("s_waitcnt lgkmcnt(0)" ::: "memory");
    __builtin_amdgcn_sched_barrier(0);
    bf16x8 ap[2];
    #pragma unroll
    for (int ks2 = 0; ks2 < 2; ++ks2) {
      int c = ks2 * 32 + l4 * 8;
      ap[ks2] = *(const bf16x8*)&Pl[wave][l15 * 64 + (c ^ ((l15 & 7) << 3))];
    }
    __builtin_amdgcn_s_setprio(1);
    #pragma unroll
    for (int dt = 0; dt < 8; ++dt) {
      int d = dt * 16 + l15;
      #pragma unroll
      for (int ks2 = 0; ks2 < 2; ++ks2) {
        int c = (ks2 * 32 + l4 * 8) ^ (((l15 >> 1) & 7) * 8);
        bf16x8 bv = *(const bf16x8*)&Vt[d * 64 + c];
        accO[dt] = __builtin_amdgcn_mfma_f32_16x16x32_bf16(ap[ks2], bv, accO[dt], 0, 0, 0);
      }
    }
    __builtin_amdgcn_s_setprio(0);
  }
  float rls[4];
  #pragma unroll
  for (int j = 0; j < 4; ++j) {
    float ls = lsum[j];
    ls += __shfl_xor(ls, 1, 16);
    ls += __shfl_xor(ls, 2, 16);
    ls += __shfl_xor(ls, 4, 16);
    ls += __shfl_xor(ls, 8, 16);
    rls[j] = 1.f / ls;
  }
  #pragma unroll
  for (int dt = 0; dt < 8; ++dt)
    #pragma unroll
    for (int j = 0; j < 4; ++j) {
      long qr = q0 + wave * 16 + l4 * 4 + j;
      long cc = (long)h * 128 + dt * 16 + l15;
      ctx[qr * 4096 + cc] = (__bf16)(accO[dt][j] * rls[j]);
    }
}

// ---------------- launch ----------------
extern "C" void kernel_launch(void* const* d_in, const int* in_sizes, int n_in,
                              void* d_out, int out_size, void* d_ws, size_t ws_size,
                              hipStream_t stream) {
  const float* hs  = (const float*)d_in[0];
  const int*   pos = (const int*)d_in[2];
  const float* Wq  = (const float*)d_in[3];
  const float* Wk  = (const float*)d_in[4];
  const float* Wv  = (const float*)d_in[5];
  const float* Wo  = (const float*)d_in[6];
  char* ws = (char*)d_ws;
  __bf16* hsb  = (__bf16*)(ws + 0L);           // 16,777,216 B
  __bf16* wqkv = (__bf16*)(ws + 16777216L);    // 50,331,648 B
  __bf16* wob  = (__bf16*)(ws + 67108864L);    // 33,554,432 B
  __bf16* qkvb = (__bf16*)(ws + 100663296L);   // 25,165,824 B  [2048][6144]
  float*  tab  = (float*)(ws + 125829120L);    //  1,048,576 B
  __bf16* ctx  = (__bf16*)(ws + 126877696L);   // 16,777,216 B  [2048][4096]

  (void)hipFuncSetAttribute(reinterpret_cast<const void*>(&gemm8p<384, true>),
                            hipFuncAttributeMaxDynamicSharedMemorySize, 131072);
  (void)hipFuncSetAttribute(reinterpret_cast<const void*>(&gemm8p<256, false>),
                            hipFuncAttributeMaxDynamicSharedMemorySize, 98304);

  CvtArgs ca;
  ca.src0 = hs;  ca.dst0 = hsb;
  ca.src1 = Wq;  ca.dst1 = wqkv;
  ca.src2 = Wk;  ca.dst2 = wqkv + 16777216L;
  ca.src3 = Wv;  ca.dst3 = wqkv + 20971520L;
  ca.src4 = Wo;  ca.dst4 = wob;
  cvt_all<<<49152, 256, 0, stream>>>(ca);
  rope_tab_k<<<512, 256, 0, stream>>>(pos, tab);

  gemm8p<384, true><<<256, 512, 131072, stream>>>(hsb, wqkv, qkvb, 4096, 6144);

  rope_apply_k<<<2560, 256, 0, stream>>>(qkvb, tab);

  flash_k<<<1024, 256, 0, stream>>>(qkvb, ctx);

  gemm8p<256, false><<<256, 512, 98304, stream>>>(ctx, wob, d_out, 4096, 4096);
}